// Round 11
// baseline (7747.298 us; speedup 1.0000x reference)
//
#include <hip/hip_runtime.h>

#define H 256
#define T_STEPS 128
#define B_BATCH 256
#define XGRP 36       // words per 32-float xs segment: 8 segments hit disjoint bank-quads
#define X2STR 72      // padded stride (words) of 64-row chunks in xsf2: q-chunks 8 banks apart

#define LOG2E 1.4426950408889634f

__device__ __forceinline__ float fexp2_(float x) {
#if __has_builtin(__builtin_amdgcn_exp2f)
    return __builtin_amdgcn_exp2f(x);
#else
    return exp2f(x);
#endif
}
__device__ __forceinline__ float frcp_(float x) {
#if __has_builtin(__builtin_amdgcn_rcpf)
    float r = __builtin_amdgcn_rcpf(x);
    return r * (2.0f - x * r);          // 1 Newton step -> ~0.5 ulp
#else
    return 1.0f / x;
#endif
}
// fast tanh: (e^{2x}-1)/(e^{2x}+1); measured bf16-exact vs np ref (rounds 8-10)
__device__ __forceinline__ float tanhf_(float x) {
    float xc = fminf(fmaxf(x, -16.f), 16.f);
    float t  = fexp2_(xc * (2.f * LOG2E));
    return (t - 1.f) * frcp_(t + 1.f);
}
__device__ __forceinline__ float sigmoidf_(float x) {
    float xc = fminf(fmaxf(x, -30.f), 30.f);
    return frcp_(1.f + fexp2_(-xc * LOG2E));
}

// ---------------- prep kernels (tiny, once per launch; cold path) ----------------

__global__ void prep_weff(const float* __restrict__ W1, const float* __restrict__ W2,
                          const float* __restrict__ b1, const float* __restrict__ b2,
                          float* __restrict__ Weff, float* __restrict__ beff) {
    int i = blockIdx.x, j = threadIdx.x;
    const float* w2row = W2 + j * H;
    float acc = 0.f;
    for (int d = 0; d < H; ++d) acc += W1[d * H + i] * w2row[d];
    Weff[i * H + j] = acc;
    if (i == 0) {
        float bacc = b2[j];
        for (int d = 0; d < H; ++d) bacc += b1[d] * w2row[d];
        beff[j] = bacc;
    }
}

__global__ void prep_whht(const float* __restrict__ Whh, float* __restrict__ WhhT) {
    int idx = blockIdx.x * blockDim.x + threadIdx.x;  // 196608
    int i = idx / 768;
    int r = idx - i * 768;
    WhhT[idx] = Whh[r * H + i];
}

__global__ void prep_wo(const float* __restrict__ Wo1, const float* __restrict__ Wo2,
                        const float* __restrict__ bo1, const float* __restrict__ bo2,
                        float* __restrict__ wo, float* __restrict__ bo) {
    int i = threadIdx.x;
    float acc = 0.f;
    for (int d = 0; d < H; ++d) acc += Wo1[d * H + i] * Wo2[d];
    wo[i] = acc;
    float p = bo1[i] * Wo2[i];
    __shared__ float red[4];
    for (int off = 32; off > 0; off >>= 1) p += __shfl_down(p, off);
    if ((i & 63) == 0) red[i >> 6] = p;
    __syncthreads();
    if (i == 0) bo[0] = red[0] + red[1] + red[2] + red[3] + bo2[0];
}

// ---------------- main scan: 1 block (1024 thr) per batch row ----------------
// RK4 (rounds 7/10, proven): tid = jp*8 + e; 32 float2 Weff weights pinned;
// EVAL = 8 broadcast b128 LDS reads + 64 FMA + folded 3-shuffle reduce + fast
// tanh.  NEW: the ENTIRE W_hh lives in registers -- thread (o=tid>>2, q=tid&3)
// owns rows [64q,64q+64) x gate-outputs {o,256+o,512+o} = 192 pinned floats
// (block total = 196608 = all of WhhT).  The per-step 639KB/CU L2 stream
// (round 10's 4.75us/step per-XCD-L2-BW floor) disappears; gh becomes 16
// conflict-free broadcast b128 reads (padded X2STR=72 stride: q-chunks hit
// disjoint bank-quads; STATIC register indexing) + 192 reg-FMAs + quad
// shfl_xor reduce.  Out-head replicated per quad, exact /4 after 6-xor
// wave reduce.  ~310 VGPRs/thread <= 512 budget at waves_per_eu(4,4)
// (which also forbids any 2-blocks/CU allocator squeeze).
// All math f32 (f16 state/weights diverge, round 2).

__global__ __attribute__((amdgpu_flat_work_group_size(1024, 1024),
                          amdgpu_waves_per_eu(4, 4)))
void ode_rnn_main(
    const float* __restrict__ b_in, const float* __restrict__ m_in,
    const float* __restrict__ trm_in, const float* __restrict__ tem_in,
    const float* __restrict__ h0,
    const float* __restrict__ Weff, const float* __restrict__ beff,
    const float* __restrict__ WhhT,
    const float* __restrict__ W_ih, const float* __restrict__ b_ih,
    const float* __restrict__ b_hh,
    const float* __restrict__ wo, const float* __restrict__ bo_p,
    float* __restrict__ out)
{
    const int tid = threadIdx.x;
    const int bb  = blockIdx.x;
    const int jp  = tid >> 3;     // RK4: column pair 0..127
    const int e   = tid & 7;      // RK4: K-slice eighth
    const int c   = e & 1;
    const int jc  = 2 * jp + c;
    const int o   = tid >> 2;     // gh: hidden index 0..255
    const int q   = tid & 3;      // gh: K-chunk (rows 64q..64q+63)

    __shared__ __align__(16) float xsb[2][8 * XGRP];     // RK4 matvec arg (dbuf)
    __shared__ __align__(16) float xsf2[4 * X2STR];      // hp, padded by chunk
    __shared__ float gh_lds[768];
    __shared__ float ohead[16];
    __shared__ float times_s[T_STEPS];
    __shared__ float bv_s[T_STEPS], trm_s[T_STEPS], tem_s[T_STEPS], m_s[T_STEPS];

    // Weff tile: rows 32e..32e+31 x cols {2jp, 2jp+1}, pinned in regs
    float2 wregv[32];
    #pragma unroll
    for (int il = 0; il < 32; ++il)
        wregv[il] = *(const float2*)&Weff[(32 * e + il) * H + 2 * jp];
    #pragma unroll
    for (int il = 0; il < 32; ++il)
        asm volatile("" : "+v"(wregv[il].x), "+v"(wregv[il].y));

    // Whh tile: rows 64q..64q+63 x outputs {o, 256+o, 512+o}, pinned in regs
    float wregh0[64], wregh1[64], wregh2[64];
    {
        const float* wb = WhhT + (64 * q) * 768 + o;
        #pragma unroll
        for (int i = 0; i < 64; ++i) {
            wregh0[i] = wb[i * 768];
            wregh1[i] = wb[i * 768 + 256];
            wregh2[i] = wb[i * 768 + 512];
        }
    }
    #pragma unroll
    for (int i = 0; i < 64; ++i)
        asm volatile("" : "+v"(wregh0[i]), "+v"(wregh1[i]), "+v"(wregh2[i]));

    if (tid < T_STEPS) {
        times_s[tid] = b_in[2 * tid];   // times identical across batch
        int bt = bb * T_STEPS + tid;
        bv_s[tid]  = b_in[2 * bt + 1];
        trm_s[tid] = trm_in[bt];
        tem_s[tid] = tem_in[bt];
        m_s[tid]   = m_in[bt];
    }

    float h = h0[bb * H + jc];
    const float be   = beff[jc];
    const float bihr = b_ih[jc], bihz = b_ih[H + jc], bihn = b_ih[2 * H + jc];
    const float bhhr = b_hh[jc], bhhz = b_hh[H + jc], bhhn = b_hh[2 * H + jc];
    const float wihr = W_ih[jc], wihz = W_ih[H + jc], wihn = W_ih[2 * H + jc];
    const float bo   = bo_p[0];
    const float wo_o = wo[o];

    // publish slot for this thread's column (valid when e < 2: then jc == 2jp+e)
    const int pubpos = (jc >> 5) * XGRP + (jc & 31);

    if (e < 2) xsb[0][pubpos] = h;     // initial publish (step 0 reads buf 0)
    __syncthreads();

    // eval: 8 broadcast b128 reads, 64 FMA (2 cols), folded 3-shuffle reduce, tanh
    #define EVAL(KOUT_) do {                                       \
        const float* xp_ = &xsb[cur][e * XGRP];                    \
        float a0_ = 0.f, a1_ = 0.f, b0_ = 0.f, b1_ = 0.f;          \
        _Pragma("unroll")                                          \
        for (int g_ = 0; g_ < 8; ++g_) {                           \
            float4 x_ = ((const float4*)xp_)[g_];                  \
            a0_ = fmaf(x_.x, wregv[4 * g_ + 0].x, a0_);            \
            b0_ = fmaf(x_.x, wregv[4 * g_ + 0].y, b0_);            \
            a1_ = fmaf(x_.y, wregv[4 * g_ + 1].x, a1_);            \
            b1_ = fmaf(x_.y, wregv[4 * g_ + 1].y, b1_);            \
            a0_ = fmaf(x_.z, wregv[4 * g_ + 2].x, a0_);            \
            b0_ = fmaf(x_.z, wregv[4 * g_ + 2].y, b0_);            \
            a1_ = fmaf(x_.w, wregv[4 * g_ + 3].x, a1_);            \
            b1_ = fmaf(x_.w, wregv[4 * g_ + 3].y, b1_);            \
        }                                                          \
        float s0_ = a0_ + a1_, s1_ = b0_ + b1_;                    \
        float v_ = (c == 0) ? s0_ : s1_;                           \
        float u_ = (c == 0) ? s1_ : s0_;                           \
        v_ += __shfl_xor(u_, 1);                                   \
        v_ += __shfl_xor(v_, 2);                                   \
        v_ += __shfl_xor(v_, 4);                                   \
        KOUT_ = tanhf_(be + v_);                                   \
    } while (0)

    // publish next matvec arg (lanes e<2, one b32 each); barrier; flip
    #define PUBLISH(V_) do {                                       \
        if (e < 2) xsb[cur ^ 1][pubpos] = (V_);                    \
        __syncthreads();                                           \
        cur ^= 1;                                                  \
    } while (0)

    float tprev = 0.f;
    #pragma unroll 1
    for (int t = 0; t < T_STEPS; ++t) {
        float t1 = times_s[t];
        float dt = (t1 - tprev) * 0.5f;   // per-substep dt (N_SUB=2)
        tprev = t1;

        int cur = 0;
        float k1, k2, k3, k4;
        #pragma unroll 1
        for (int s = 0; s < 2; ++s) {
            EVAL(k1); PUBLISH(fmaf(0.5f * dt, k1, h));
            EVAL(k2); PUBLISH(fmaf(0.5f * dt, k2, h));
            EVAL(k3); PUBLISH(fmaf(dt, k3, h));
            EVAL(k4);
            h = fmaf(dt * (1.f / 6.f), k1 + 2.f * (k2 + k3) + k4, h);
            if (s == 0) PUBLISH(h);   // substep-2 k1 reads h
        }

        // stage hp into padded xsf2 (row r at r + 8*(r>>6))
        if (e < 2) xsf2[jc + 8 * (jc >> 6)] = h;
        __syncthreads();

        // ---- gh from registers (ALL 1024 threads; no global traffic) ----
        {
            const float* xb = &xsf2[X2STR * q];   // rows 64q.. (bank-offset 8q)
            float pg0 = 0.f, pg1 = 0.f, pg2 = 0.f;
            #pragma unroll
            for (int ii = 0; ii < 16; ++ii) {
                float4 x = *(const float4*)(xb + 4 * ii);
                pg0 = fmaf(x.x, wregh0[4 * ii + 0], pg0);
                pg1 = fmaf(x.x, wregh1[4 * ii + 0], pg1);
                pg2 = fmaf(x.x, wregh2[4 * ii + 0], pg2);
                pg0 = fmaf(x.y, wregh0[4 * ii + 1], pg0);
                pg1 = fmaf(x.y, wregh1[4 * ii + 1], pg1);
                pg2 = fmaf(x.y, wregh2[4 * ii + 1], pg2);
                pg0 = fmaf(x.z, wregh0[4 * ii + 2], pg0);
                pg1 = fmaf(x.z, wregh1[4 * ii + 2], pg1);
                pg2 = fmaf(x.z, wregh2[4 * ii + 2], pg2);
                pg0 = fmaf(x.w, wregh0[4 * ii + 3], pg0);
                pg1 = fmaf(x.w, wregh1[4 * ii + 3], pg1);
                pg2 = fmaf(x.w, wregh2[4 * ii + 3], pg2);
            }
            // quad reduce over q (commutative adds -> bit-identical in quad)
            pg0 += __shfl_xor(pg0, 1); pg0 += __shfl_xor(pg0, 2);
            pg1 += __shfl_xor(pg1, 1); pg1 += __shfl_xor(pg1, 2);
            pg2 += __shfl_xor(pg2, 1); pg2 += __shfl_xor(pg2, 2);
            float pgsel = (q == 0) ? pg0 : (q == 1) ? pg1 : pg2;
            if (q < 3) gh_lds[q * 256 + o] = pgsel;

            // out-head: every lane computes hp[o]*wo[o] (quad-replicated);
            // 64-lane xor reduce = 4x the 16-o sum; /4 is exact.
            float ph = xsf2[o + 8 * (o >> 6)] * wo_o;
            ph += __shfl_xor(ph, 1);  ph += __shfl_xor(ph, 2);
            ph += __shfl_xor(ph, 4);  ph += __shfl_xor(ph, 8);
            ph += __shfl_xor(ph, 16); ph += __shfl_xor(ph, 32);
            if ((tid & 63) == 0) ohead[tid >> 6] = ph * 0.25f;
        }
        __syncthreads();

        // gates: ALL threads compute for their jc (replicated, bit-identical)
        {
            float osum = 0.f;
            #pragma unroll
            for (int w = 0; w < 16; ++w) osum += ohead[w];
            float outv = tanhf_(osum + bo);
            float bv = bv_s[t], trm = trm_s[t], tem = tem_s[t], mv = m_s[t];
            float ghr = gh_lds[jc] + bhhr;
            float ghz = gh_lds[256 + jc] + bhhz;
            float ghn = gh_lds[512 + jc] + bhhn;
            float x1v = bv * trm, x2v = outv * tem;

            float r1 = sigmoidf_(fmaf(x1v, wihr, bihr) + ghr);
            float z1 = sigmoidf_(fmaf(x1v, wihz, bihz) + ghz);
            float n1 = tanhf_(fmaf(x1v, wihn, bihn) + r1 * ghn);
            float h1 = (1.f - z1) * n1 + z1 * h;

            float r2 = sigmoidf_(fmaf(x2v, wihr, bihr) + ghr);
            float z2 = sigmoidf_(fmaf(x2v, wihz, bihz) + ghz);
            float n2 = tanhf_(fmaf(x2v, wihn, bihn) + r2 * ghn);
            float h2 = (1.f - z2) * n2 + z2 * h;

            if (tid == 0) out[bb * T_STEPS + t] = outv;
            h = trm * h1 + tem * h2 + (1.f - mv) * h;
        }

        // publish h_new for next step's first eval (reads buf 0)
        if (e < 2) xsb[0][pubpos] = h;
        __syncthreads();
    }
    #undef EVAL
    #undef PUBLISH
}

// ---------------- launcher ----------------

extern "C" void kernel_launch(void* const* d_in, const int* in_sizes, int n_in,
                              void* d_out, int out_size, void* d_ws, size_t ws_size,
                              hipStream_t stream) {
    const float* b_in = (const float*)d_in[0];
    const float* m_in = (const float*)d_in[1];
    const float* trm  = (const float*)d_in[2];
    const float* tem  = (const float*)d_in[3];
    const float* h0   = (const float*)d_in[4];
    const float* W1   = (const float*)d_in[5];
    const float* b1   = (const float*)d_in[6];
    const float* W2   = (const float*)d_in[7];
    const float* b2   = (const float*)d_in[8];
    const float* W_ih = (const float*)d_in[9];
    const float* W_hh = (const float*)d_in[10];
    const float* b_ih = (const float*)d_in[11];
    const float* b_hh = (const float*)d_in[12];
    const float* Wo1  = (const float*)d_in[13];
    const float* bo1  = (const float*)d_in[14];
    const float* Wo2  = (const float*)d_in[15];
    const float* bo2  = (const float*)d_in[16];

    float* ws   = (float*)d_ws;
    float* Weff = ws;             // 65536
    float* beff = Weff + 65536;   // 256
    float* WhhT = beff + 256;     // 196608
    float* wo   = WhhT + 196608;  // 256
    float* bo   = wo + 256;       // 1

    prep_weff<<<256, 256, 0, stream>>>(W1, W2, b1, b2, Weff, beff);
    prep_whht<<<192, 1024, 0, stream>>>(W_hh, WhhT);
    prep_wo<<<1, 256, 0, stream>>>(Wo1, Wo2, bo1, bo2, wo, bo);

    ode_rnn_main<<<B_BATCH, 1024, 0, stream>>>(b_in, m_in, trm, tem, h0,
                                               Weff, beff, WhhT,
                                               W_ih, b_ih, b_hh, wo, bo,
                                               (float*)d_out);
}

// Round 12
// 3164.175 us; speedup vs baseline: 2.4484x; 2.4484x over previous
//
#include <hip/hip_runtime.h>

#define H 256
#define T_STEPS 128
#define B_BATCH 256
#define I_LDS 48      // WhhT rows [0,48) persistent in LDS (48*768*4B = 147456 B)
#define XGRP 36       // words per 32-float xs segment: 8 segments hit disjoint bank-quads

#define LOG2E 1.4426950408889634f

__device__ __forceinline__ float fexp2_(float x) {
#if __has_builtin(__builtin_amdgcn_exp2f)
    return __builtin_amdgcn_exp2f(x);
#else
    return exp2f(x);
#endif
}
__device__ __forceinline__ float frcp_(float x) {
#if __has_builtin(__builtin_amdgcn_rcpf)
    float r = __builtin_amdgcn_rcpf(x);
    return r * (2.0f - x * r);          // 1 Newton step -> ~0.5 ulp
#else
    return 1.0f / x;
#endif
}
// fast tanh: (e^{2x}-1)/(e^{2x}+1); measured bf16-exact vs np ref (rounds 8-10)
__device__ __forceinline__ float tanhf_(float x) {
    float xc = fminf(fmaxf(x, -16.f), 16.f);
    float t  = fexp2_(xc * (2.f * LOG2E));
    return (t - 1.f) * frcp_(t + 1.f);
}
__device__ __forceinline__ float sigmoidf_(float x) {
    float xc = fminf(fmaxf(x, -30.f), 30.f);
    return frcp_(1.f + fexp2_(-xc * LOG2E));
}

// ---------------- prep kernels (tiny, once per launch; cold path) ----------------

__global__ void prep_weff(const float* __restrict__ W1, const float* __restrict__ W2,
                          const float* __restrict__ b1, const float* __restrict__ b2,
                          float* __restrict__ Weff, float* __restrict__ beff) {
    int i = blockIdx.x, j = threadIdx.x;
    const float* w2row = W2 + j * H;
    float acc = 0.f;
    for (int d = 0; d < H; ++d) acc += W1[d * H + i] * w2row[d];
    Weff[i * H + j] = acc;
    if (i == 0) {
        float bacc = b2[j];
        for (int d = 0; d < H; ++d) bacc += b1[d] * w2row[d];
        beff[j] = bacc;
    }
}

__global__ void prep_whht(const float* __restrict__ Whh, float* __restrict__ WhhT) {
    int idx = blockIdx.x * blockDim.x + threadIdx.x;  // 196608
    int i = idx / 768;
    int r = idx - i * 768;
    WhhT[idx] = Whh[r * H + i];
}

__global__ void prep_wo(const float* __restrict__ Wo1, const float* __restrict__ Wo2,
                        const float* __restrict__ bo1, const float* __restrict__ bo2,
                        float* __restrict__ wo, float* __restrict__ bo) {
    int i = threadIdx.x;
    float acc = 0.f;
    for (int d = 0; d < H; ++d) acc += Wo1[d * H + i] * Wo2[d];
    wo[i] = acc;
    float p = bo1[i] * Wo2[i];
    __shared__ float red[4];
    for (int off = 32; off > 0; off >>= 1) p += __shfl_down(p, off);
    if ((i & 63) == 0) red[i >> 6] = p;
    __syncthreads();
    if (i == 0) bo[0] = red[0] + red[1] + red[2] + red[3] + bo2[0];
}

// ---------------- main scan: 1 block (1024 thr) per batch row ----------------
// Round-10 structure (best: 2029us) with ONE change: gh's L2 part reads the
// ORIGINAL W_hh row-contiguously.  Thread r owns gh[r] = sum_i hp[i]*Whh[r,i];
// cols [48,256) = 52 b128 loads from ONE base (offsets 192..1008B all fold
// into the 13-bit immediate) -> ~1 addr instr instead of ~200, 52 load
// issues instead of 208.  Same L2 transaction count (each 64B line fully
// consumed by one lane within 4 adjacent unrolled loads).  LDS part
// (rows [0,48)) keeps the proven conflict-free stride-768 walk on WhhT.
// NOTE (round 11): weights can NEVER be fully CU-resident in f32 -- RF is
// 512KB/CU total (128 regs/thread max at 16 waves), LDS 160KB, need 1MB.
// All math f32 (f16 state/weights diverge, round 2).

__global__ __attribute__((amdgpu_flat_work_group_size(1024, 1024),
                          amdgpu_waves_per_eu(4, 4)))
void ode_rnn_main(
    const float* __restrict__ b_in, const float* __restrict__ m_in,
    const float* __restrict__ trm_in, const float* __restrict__ tem_in,
    const float* __restrict__ h0,
    const float* __restrict__ Weff, const float* __restrict__ beff,
    const float* __restrict__ WhhT, const float* __restrict__ Whh,
    const float* __restrict__ W_ih, const float* __restrict__ b_ih,
    const float* __restrict__ b_hh,
    const float* __restrict__ wo, const float* __restrict__ bo_p,
    float* __restrict__ out)
{
    const int tid = threadIdx.x;
    const int bb  = blockIdx.x;
    const int jp  = tid >> 3;     // column pair 0..127
    const int e   = tid & 7;      // K-slice eighth
    const int c   = e & 1;
    const int jc  = 2 * jp + c;

    __shared__ float whh_lds[I_LDS * 768];               // 147456 B
    __shared__ __align__(16) float xsb[2][8 * XGRP];     // 2304 B
    __shared__ __align__(16) float xsf[H];               // hp (linear)
    __shared__ float gh_lds[768];
    __shared__ float red[4];
    __shared__ float times_s[T_STEPS];
    __shared__ float bv_s[T_STEPS], trm_s[T_STEPS], tem_s[T_STEPS], m_s[T_STEPS];

    // Weff tile: rows 32e..32e+31 x cols {2jp, 2jp+1}, pinned in regs
    float2 wregv[32];
    #pragma unroll
    for (int il = 0; il < 32; ++il)
        wregv[il] = *(const float2*)&Weff[(32 * e + il) * H + 2 * jp];
    #pragma unroll
    for (int il = 0; il < 32; ++il)
        asm volatile("" : "+v"(wregv[il].x), "+v"(wregv[il].y));

    // stage WhhT rows [0,I_LDS) + per-step scalars
    for (int k = tid; k < I_LDS * 768; k += 1024) whh_lds[k] = WhhT[k];
    if (tid < T_STEPS) {
        times_s[tid] = b_in[2 * tid];   // times identical across batch
        int bt = bb * T_STEPS + tid;
        bv_s[tid]  = b_in[2 * bt + 1];
        trm_s[tid] = trm_in[bt];
        tem_s[tid] = tem_in[bt];
        m_s[tid]   = m_in[bt];
    }

    float h = h0[bb * H + jc];
    const float be   = beff[jc];
    const float bihr = b_ih[jc], bihz = b_ih[H + jc], bihn = b_ih[2 * H + jc];
    const float bhhr = b_hh[jc], bhhz = b_hh[H + jc], bhhn = b_hh[2 * H + jc];
    const float wihr = W_ih[jc], wihz = W_ih[H + jc], wihn = W_ih[2 * H + jc];
    const float bo   = bo_p[0];
    const float wo_t = (tid >= 768) ? wo[tid - 768] : 0.f;

    // publish slot for this thread's column (valid when e < 2: then jc == 2jp+e)
    const int pubpos = (jc >> 5) * XGRP + (jc & 31);

    if (e < 2) xsb[0][pubpos] = h;     // initial publish (step 0 reads buf 0)
    __syncthreads();

    // eval: 8 broadcast b128 reads, 64 FMA (2 cols), folded 3-shuffle reduce, tanh
    #define EVAL(KOUT_) do {                                       \
        const float* xp_ = &xsb[cur][e * XGRP];                    \
        float a0_ = 0.f, a1_ = 0.f, b0_ = 0.f, b1_ = 0.f;          \
        _Pragma("unroll")                                          \
        for (int g_ = 0; g_ < 8; ++g_) {                           \
            float4 x_ = ((const float4*)xp_)[g_];                  \
            a0_ = fmaf(x_.x, wregv[4 * g_ + 0].x, a0_);            \
            b0_ = fmaf(x_.x, wregv[4 * g_ + 0].y, b0_);            \
            a1_ = fmaf(x_.y, wregv[4 * g_ + 1].x, a1_);            \
            b1_ = fmaf(x_.y, wregv[4 * g_ + 1].y, b1_);            \
            a0_ = fmaf(x_.z, wregv[4 * g_ + 2].x, a0_);            \
            b0_ = fmaf(x_.z, wregv[4 * g_ + 2].y, b0_);            \
            a1_ = fmaf(x_.w, wregv[4 * g_ + 3].x, a1_);            \
            b1_ = fmaf(x_.w, wregv[4 * g_ + 3].y, b1_);            \
        }                                                          \
        float s0_ = a0_ + a1_, s1_ = b0_ + b1_;                    \
        float v_ = (c == 0) ? s0_ : s1_;                           \
        float u_ = (c == 0) ? s1_ : s0_;                           \
        v_ += __shfl_xor(u_, 1);                                   \
        v_ += __shfl_xor(v_, 2);                                   \
        v_ += __shfl_xor(v_, 4);                                   \
        KOUT_ = tanhf_(be + v_);                                   \
    } while (0)

    // publish next matvec arg (lanes e<2, one b32 each); barrier; flip
    #define PUBLISH(V_) do {                                       \
        if (e < 2) xsb[cur ^ 1][pubpos] = (V_);                    \
        __syncthreads();                                           \
        cur ^= 1;                                                  \
    } while (0)

    float tprev = 0.f;
    #pragma unroll 1
    for (int t = 0; t < T_STEPS; ++t) {
        float t1 = times_s[t];
        float dt = (t1 - tprev) * 0.5f;   // per-substep dt (N_SUB=2)
        tprev = t1;

        int cur = 0;
        float k1, k2, k3, k4;
        #pragma unroll 1
        for (int s = 0; s < 2; ++s) {
            EVAL(k1); PUBLISH(fmaf(0.5f * dt, k1, h));
            EVAL(k2); PUBLISH(fmaf(0.5f * dt, k2, h));
            EVAL(k3); PUBLISH(fmaf(dt, k3, h));
            EVAL(k4);
            h = fmaf(dt * (1.f / 6.f), k1 + 2.f * (k2 + k3) + k4, h);
            if (s == 0) PUBLISH(h);   // substep-2 k1 reads h
        }

        // stage hp (linear) for gh + out head
        if (e < 2) xsf[jc] = h;
        __syncthreads();

        // gh[tid] = sum_i hp[i] * Whh[tid, i]  (threads 0..767)
        //  L2 cols [48,256): 52 b128 loads from ONE base, offsets all
        //  immediate-foldable; each 64B line fully consumed by its lane.
        //  LDS cols [0,48): proven conflict-free stride-768 walk on WhhT.
        // || out-head dot (waves 12..15)
        if (tid < 768) {
            const float* wrow = Whh + tid * H;
            float c0 = 0.f, c1 = 0.f, c2 = 0.f, c3 = 0.f;
            #pragma unroll 13
            for (int ii = 0; ii < 52; ++ii) {
                float4 w = *(const float4*)(wrow + I_LDS + 4 * ii);
                float4 x = *(const float4*)(xsf + I_LDS + 4 * ii);
                c0 = fmaf(x.x, w.x, c0);
                c1 = fmaf(x.y, w.y, c1);
                c2 = fmaf(x.z, w.z, c2);
                c3 = fmaf(x.w, w.w, c3);
            }
            float g0 = 0.f, g1 = 0.f, g2 = 0.f, g3 = 0.f;
            const float* wl = whh_lds + tid;
            #pragma unroll 4
            for (int i = 0; i < I_LDS; i += 4) {
                float4 xv = *(const float4*)(xsf + i);
                g0 = fmaf(xv.x, wl[(i + 0) * 768], g0);
                g1 = fmaf(xv.y, wl[(i + 1) * 768], g1);
                g2 = fmaf(xv.z, wl[(i + 2) * 768], g2);
                g3 = fmaf(xv.w, wl[(i + 3) * 768], g3);
            }
            gh_lds[tid] = ((c0 + c1) + (c2 + c3)) + ((g0 + g1) + (g2 + g3));
        } else {
            float p = xsf[tid - 768] * wo_t;
            #pragma unroll
            for (int off = 32; off > 0; off >>= 1) p += __shfl_down(p, off);
            if ((tid & 63) == 0) red[(tid - 768) >> 6] = p;
        }
        __syncthreads();

        // gates: ALL threads compute for their jc (replicated, bit-identical)
        {
            float outv = tanhf_(red[0] + red[1] + red[2] + red[3] + bo);
            float bv = bv_s[t], trm = trm_s[t], tem = tem_s[t], mv = m_s[t];
            float ghr = gh_lds[jc] + bhhr;
            float ghz = gh_lds[256 + jc] + bhhz;
            float ghn = gh_lds[512 + jc] + bhhn;
            float x1v = bv * trm, x2v = outv * tem;

            float r1 = sigmoidf_(fmaf(x1v, wihr, bihr) + ghr);
            float z1 = sigmoidf_(fmaf(x1v, wihz, bihz) + ghz);
            float n1 = tanhf_(fmaf(x1v, wihn, bihn) + r1 * ghn);
            float h1 = (1.f - z1) * n1 + z1 * h;

            float r2 = sigmoidf_(fmaf(x2v, wihr, bihr) + ghr);
            float z2 = sigmoidf_(fmaf(x2v, wihz, bihz) + ghz);
            float n2 = tanhf_(fmaf(x2v, wihn, bihn) + r2 * ghn);
            float h2 = (1.f - z2) * n2 + z2 * h;

            if (tid == 0) out[bb * T_STEPS + t] = outv;
            h = trm * h1 + tem * h2 + (1.f - mv) * h;
        }

        // publish h_new for next step's first eval (reads buf 0)
        if (e < 2) xsb[0][pubpos] = h;
        __syncthreads();
    }
    #undef EVAL
    #undef PUBLISH
}

// ---------------- launcher ----------------

extern "C" void kernel_launch(void* const* d_in, const int* in_sizes, int n_in,
                              void* d_out, int out_size, void* d_ws, size_t ws_size,
                              hipStream_t stream) {
    const float* b_in = (const float*)d_in[0];
    const float* m_in = (const float*)d_in[1];
    const float* trm  = (const float*)d_in[2];
    const float* tem  = (const float*)d_in[3];
    const float* h0   = (const float*)d_in[4];
    const float* W1   = (const float*)d_in[5];
    const float* b1   = (const float*)d_in[6];
    const float* W2   = (const float*)d_in[7];
    const float* b2   = (const float*)d_in[8];
    const float* W_ih = (const float*)d_in[9];
    const float* W_hh = (const float*)d_in[10];
    const float* b_ih = (const float*)d_in[11];
    const float* b_hh = (const float*)d_in[12];
    const float* Wo1  = (const float*)d_in[13];
    const float* bo1  = (const float*)d_in[14];
    const float* Wo2  = (const float*)d_in[15];
    const float* bo2  = (const float*)d_in[16];

    float* ws   = (float*)d_ws;
    float* Weff = ws;             // 65536
    float* beff = Weff + 65536;   // 256
    float* WhhT = beff + 256;     // 196608
    float* wo   = WhhT + 196608;  // 256
    float* bo   = wo + 256;       // 1

    prep_weff<<<256, 256, 0, stream>>>(W1, W2, b1, b2, Weff, beff);
    prep_whht<<<192, 1024, 0, stream>>>(W_hh, WhhT);
    prep_wo<<<1, 256, 0, stream>>>(Wo1, Wo2, bo1, bo2, wo, bo);

    ode_rnn_main<<<B_BATCH, 1024, 0, stream>>>(b_in, m_in, trm, tem, h0,
                                               Weff, beff, WhhT, W_hh,
                                               W_ih, b_ih, b_hh, wo, bo,
                                               (float*)d_out);
}

// Round 13
// 2094.264 us; speedup vs baseline: 3.6993x; 1.5109x over previous
//
#include <hip/hip_runtime.h>

#define H 256
#define T_STEPS 128
#define B_BATCH 256
#define I_LDS 48      // WhhT rows [0,48) persistent in LDS as f32 (147456 B)
#define N_P16 104     // packed f16 row-pairs covering rows [48,256)
#define XGRP 36       // words per 32-float xs segment: 8 segments hit disjoint bank-quads

#define LOG2E 1.4426950408889634f

union CVH { unsigned int u; _Float16 h[2]; };

__device__ __forceinline__ float fexp2_(float x) {
#if __has_builtin(__builtin_amdgcn_exp2f)
    return __builtin_amdgcn_exp2f(x);
#else
    return exp2f(x);
#endif
}
__device__ __forceinline__ float frcp_(float x) {
#if __has_builtin(__builtin_amdgcn_rcpf)
    float r = __builtin_amdgcn_rcpf(x);
    return r * (2.0f - x * r);          // 1 Newton step -> ~0.5 ulp
#else
    return 1.0f / x;
#endif
}
// fast tanh/sigmoid: measured bf16-exact vs np ref (rounds 8-10)
__device__ __forceinline__ float tanhf_(float x) {
    float xc = fminf(fmaxf(x, -16.f), 16.f);
    float t  = fexp2_(xc * (2.f * LOG2E));
    return (t - 1.f) * frcp_(t + 1.f);
}
__device__ __forceinline__ float sigmoidf_(float x) {
    float xc = fminf(fmaxf(x, -30.f), 30.f);
    return frcp_(1.f + fexp2_(-xc * LOG2E));
}

// ---------------- prep kernels (tiny, once per launch; cold path) ----------------

__global__ void prep_weff(const float* __restrict__ W1, const float* __restrict__ W2,
                          const float* __restrict__ b1, const float* __restrict__ b2,
                          float* __restrict__ Weff, float* __restrict__ beff) {
    int i = blockIdx.x, j = threadIdx.x;
    const float* w2row = W2 + j * H;
    float acc = 0.f;
    for (int d = 0; d < H; ++d) acc += W1[d * H + i] * w2row[d];
    Weff[i * H + j] = acc;
    if (i == 0) {
        float bacc = b2[j];
        for (int d = 0; d < H; ++d) bacc += b1[d] * w2row[d];
        beff[j] = bacc;
    }
}

__global__ void prep_whht(const float* __restrict__ Whh, float* __restrict__ WhhT) {
    int idx = blockIdx.x * blockDim.x + threadIdx.x;  // 196608
    int i = idx / 768;
    int r = idx - i * 768;
    WhhT[idx] = Whh[r * H + i];
}

// pack rows {48+2i2, 49+2i2} col r of WhhT into one dword of 2 f16 (RNE)
__global__ void prep_whh16(const float* __restrict__ WhhT, unsigned int* __restrict__ W16) {
    int idx = blockIdx.x * blockDim.x + threadIdx.x;  // 79872
    if (idx >= N_P16 * 768) return;
    int i2 = idx / 768;
    int r  = idx - i2 * 768;
    CVH cv;
    cv.h[0] = (_Float16)WhhT[(I_LDS + 2 * i2) * 768 + r];
    cv.h[1] = (_Float16)WhhT[(I_LDS + 2 * i2 + 1) * 768 + r];
    W16[idx] = cv.u;
}

__global__ void prep_wo(const float* __restrict__ Wo1, const float* __restrict__ Wo2,
                        const float* __restrict__ bo1, const float* __restrict__ bo2,
                        float* __restrict__ wo, float* __restrict__ bo) {
    int i = threadIdx.x;
    float acc = 0.f;
    for (int d = 0; d < H; ++d) acc += Wo1[d * H + i] * Wo2[d];
    wo[i] = acc;
    float p = bo1[i] * Wo2[i];
    __shared__ float red[4];
    for (int off = 32; off > 0; off >>= 1) p += __shfl_down(p, off);
    if ((i & 63) == 0) red[i >> 6] = p;
    __syncthreads();
    if (i == 0) bo[0] = red[0] + red[1] + red[2] + red[3] + bo2[0];
}

// ---------------- main scan: 1 block (1024 thr) per batch row ----------------
// Round-10 structure (best: 2029us; all gh restructures failed r8/r9/r11/r12)
// with ONE change: the L2-streamed Whh portion (rows [48,256)) is f16-packed
// in the SAME transposed layout -- consecutive lanes read consecutive dwords
// (256B/wave-load, the proven coalescing), 104 load issues instead of 208,
// stream bytes 639KB -> 319KB per CU per step (the 4.75us/step per-XCD-L2
// floor roughly halves).  hp, accumulation, LDS-cached rows, and the whole
// RK4 trajectory stay f32 (round 2 failed by putting the INTEGRATION in
// f16; this is one-sided weight rounding on the GRU input only).
// All else byte-identical to round 10.

__global__ __attribute__((amdgpu_flat_work_group_size(1024, 1024),
                          amdgpu_waves_per_eu(4, 4)))
void ode_rnn_main(
    const float* __restrict__ b_in, const float* __restrict__ m_in,
    const float* __restrict__ trm_in, const float* __restrict__ tem_in,
    const float* __restrict__ h0,
    const float* __restrict__ Weff, const float* __restrict__ beff,
    const float* __restrict__ WhhT, const unsigned int* __restrict__ Whh16,
    const float* __restrict__ W_ih, const float* __restrict__ b_ih,
    const float* __restrict__ b_hh,
    const float* __restrict__ wo, const float* __restrict__ bo_p,
    float* __restrict__ out)
{
    const int tid = threadIdx.x;
    const int bb  = blockIdx.x;
    const int jp  = tid >> 3;     // column pair 0..127
    const int e   = tid & 7;      // K-slice eighth
    const int c   = e & 1;
    const int jc  = 2 * jp + c;

    __shared__ float whh_lds[I_LDS * 768];               // 147456 B
    __shared__ __align__(16) float xsb[2][8 * XGRP];     // 2304 B
    __shared__ __align__(16) float xsf[H];               // hp (linear)
    __shared__ float gh_lds[768];
    __shared__ float red[4];
    __shared__ float times_s[T_STEPS];
    __shared__ float bv_s[T_STEPS], trm_s[T_STEPS], tem_s[T_STEPS], m_s[T_STEPS];

    // Weff tile: rows 32e..32e+31 x cols {2jp, 2jp+1}, pinned in regs
    float2 wregv[32];
    #pragma unroll
    for (int il = 0; il < 32; ++il)
        wregv[il] = *(const float2*)&Weff[(32 * e + il) * H + 2 * jp];
    #pragma unroll
    for (int il = 0; il < 32; ++il)
        asm volatile("" : "+v"(wregv[il].x), "+v"(wregv[il].y));

    // stage WhhT rows [0,I_LDS) + per-step scalars
    for (int k = tid; k < I_LDS * 768; k += 1024) whh_lds[k] = WhhT[k];
    if (tid < T_STEPS) {
        times_s[tid] = b_in[2 * tid];   // times identical across batch
        int bt = bb * T_STEPS + tid;
        bv_s[tid]  = b_in[2 * bt + 1];
        trm_s[tid] = trm_in[bt];
        tem_s[tid] = tem_in[bt];
        m_s[tid]   = m_in[bt];
    }

    float h = h0[bb * H + jc];
    const float be   = beff[jc];
    const float bihr = b_ih[jc], bihz = b_ih[H + jc], bihn = b_ih[2 * H + jc];
    const float bhhr = b_hh[jc], bhhz = b_hh[H + jc], bhhn = b_hh[2 * H + jc];
    const float wihr = W_ih[jc], wihz = W_ih[H + jc], wihn = W_ih[2 * H + jc];
    const float bo   = bo_p[0];
    const float wo_t = (tid >= 768) ? wo[tid - 768] : 0.f;

    // publish slot for this thread's column (valid when e < 2: then jc == 2jp+e)
    const int pubpos = (jc >> 5) * XGRP + (jc & 31);

    if (e < 2) xsb[0][pubpos] = h;     // initial publish (step 0 reads buf 0)
    __syncthreads();

    // eval: 8 broadcast b128 reads, 64 FMA (2 cols), folded 3-shuffle reduce, tanh
    #define EVAL(KOUT_) do {                                       \
        const float* xp_ = &xsb[cur][e * XGRP];                    \
        float a0_ = 0.f, a1_ = 0.f, b0_ = 0.f, b1_ = 0.f;          \
        _Pragma("unroll")                                          \
        for (int g_ = 0; g_ < 8; ++g_) {                           \
            float4 x_ = ((const float4*)xp_)[g_];                  \
            a0_ = fmaf(x_.x, wregv[4 * g_ + 0].x, a0_);            \
            b0_ = fmaf(x_.x, wregv[4 * g_ + 0].y, b0_);            \
            a1_ = fmaf(x_.y, wregv[4 * g_ + 1].x, a1_);            \
            b1_ = fmaf(x_.y, wregv[4 * g_ + 1].y, b1_);            \
            a0_ = fmaf(x_.z, wregv[4 * g_ + 2].x, a0_);            \
            b0_ = fmaf(x_.z, wregv[4 * g_ + 2].y, b0_);            \
            a1_ = fmaf(x_.w, wregv[4 * g_ + 3].x, a1_);            \
            b1_ = fmaf(x_.w, wregv[4 * g_ + 3].y, b1_);            \
        }                                                          \
        float s0_ = a0_ + a1_, s1_ = b0_ + b1_;                    \
        float v_ = (c == 0) ? s0_ : s1_;                           \
        float u_ = (c == 0) ? s1_ : s0_;                           \
        v_ += __shfl_xor(u_, 1);                                   \
        v_ += __shfl_xor(v_, 2);                                   \
        v_ += __shfl_xor(v_, 4);                                   \
        KOUT_ = tanhf_(be + v_);                                   \
    } while (0)

    // publish next matvec arg (lanes e<2, one b32 each); barrier; flip
    #define PUBLISH(V_) do {                                       \
        if (e < 2) xsb[cur ^ 1][pubpos] = (V_);                    \
        __syncthreads();                                           \
        cur ^= 1;                                                  \
    } while (0)

    float tprev = 0.f;
    #pragma unroll 1
    for (int t = 0; t < T_STEPS; ++t) {
        float t1 = times_s[t];
        float dt = (t1 - tprev) * 0.5f;   // per-substep dt (N_SUB=2)
        tprev = t1;

        int cur = 0;
        float k1, k2, k3, k4;
        #pragma unroll 1
        for (int s = 0; s < 2; ++s) {
            EVAL(k1); PUBLISH(fmaf(0.5f * dt, k1, h));
            EVAL(k2); PUBLISH(fmaf(0.5f * dt, k2, h));
            EVAL(k3); PUBLISH(fmaf(dt, k3, h));
            EVAL(k4);
            h = fmaf(dt * (1.f / 6.f), k1 + 2.f * (k2 + k3) + k4, h);
            if (s == 0) PUBLISH(h);   // substep-2 k1 reads h
        }

        // stage hp (linear) for gh + out head
        if (e < 2) xsf[jc] = h;
        __syncthreads();

        // gh = hp @ W_hh^T (threads 0..767):
        //  rows [0,48): f32 from LDS, proven conflict-free stride-768 walk.
        //  rows [48,256): f16-packed transposed stream -- consecutive lanes
        //  read consecutive dwords (256B/wave), 104 issues, bytes halved.
        // || out-head dot (waves 12..15)
        if (tid < 768) {
            float c0 = 0.f, c1 = 0.f, c2 = 0.f, c3 = 0.f;
            const unsigned int* wp = Whh16 + tid;
            #pragma unroll 13
            for (int ii = 0; ii < N_P16; ii += 2) {
                float4 xv = *(const float4*)(xsf + I_LDS + 2 * ii);
                CVH ca, cb;
                ca.u = wp[ii * 768];
                cb.u = wp[(ii + 1) * 768];
                c0 = fmaf(xv.x, (float)ca.h[0], c0);
                c1 = fmaf(xv.y, (float)ca.h[1], c1);
                c2 = fmaf(xv.z, (float)cb.h[0], c2);
                c3 = fmaf(xv.w, (float)cb.h[1], c3);
            }
            float g0 = 0.f, g1 = 0.f, g2 = 0.f, g3 = 0.f;
            const float* wl = whh_lds + tid;
            #pragma unroll 4
            for (int i = 0; i < I_LDS; i += 4) {
                float4 xv = *(const float4*)(xsf + i);
                g0 = fmaf(xv.x, wl[(i + 0) * 768], g0);
                g1 = fmaf(xv.y, wl[(i + 1) * 768], g1);
                g2 = fmaf(xv.z, wl[(i + 2) * 768], g2);
                g3 = fmaf(xv.w, wl[(i + 3) * 768], g3);
            }
            gh_lds[tid] = ((c0 + c1) + (c2 + c3)) + ((g0 + g1) + (g2 + g3));
        } else {
            float p = xsf[tid - 768] * wo_t;
            #pragma unroll
            for (int off = 32; off > 0; off >>= 1) p += __shfl_down(p, off);
            if ((tid & 63) == 0) red[(tid - 768) >> 6] = p;
        }
        __syncthreads();

        // gates: ALL threads compute for their jc (replicated, bit-identical)
        {
            float outv = tanhf_(red[0] + red[1] + red[2] + red[3] + bo);
            float bv = bv_s[t], trm = trm_s[t], tem = tem_s[t], mv = m_s[t];
            float ghr = gh_lds[jc] + bhhr;
            float ghz = gh_lds[256 + jc] + bhhz;
            float ghn = gh_lds[512 + jc] + bhhn;
            float x1v = bv * trm, x2v = outv * tem;

            float r1 = sigmoidf_(fmaf(x1v, wihr, bihr) + ghr);
            float z1 = sigmoidf_(fmaf(x1v, wihz, bihz) + ghz);
            float n1 = tanhf_(fmaf(x1v, wihn, bihn) + r1 * ghn);
            float h1 = (1.f - z1) * n1 + z1 * h;

            float r2 = sigmoidf_(fmaf(x2v, wihr, bihr) + ghr);
            float z2 = sigmoidf_(fmaf(x2v, wihz, bihz) + ghz);
            float n2 = tanhf_(fmaf(x2v, wihn, bihn) + r2 * ghn);
            float h2 = (1.f - z2) * n2 + z2 * h;

            if (tid == 0) out[bb * T_STEPS + t] = outv;
            h = trm * h1 + tem * h2 + (1.f - mv) * h;
        }

        // publish h_new for next step's first eval (reads buf 0)
        if (e < 2) xsb[0][pubpos] = h;
        __syncthreads();
    }
    #undef EVAL
    #undef PUBLISH
}

// ---------------- launcher ----------------

extern "C" void kernel_launch(void* const* d_in, const int* in_sizes, int n_in,
                              void* d_out, int out_size, void* d_ws, size_t ws_size,
                              hipStream_t stream) {
    const float* b_in = (const float*)d_in[0];
    const float* m_in = (const float*)d_in[1];
    const float* trm  = (const float*)d_in[2];
    const float* tem  = (const float*)d_in[3];
    const float* h0   = (const float*)d_in[4];
    const float* W1   = (const float*)d_in[5];
    const float* b1   = (const float*)d_in[6];
    const float* W2   = (const float*)d_in[7];
    const float* b2   = (const float*)d_in[8];
    const float* W_ih = (const float*)d_in[9];
    const float* W_hh = (const float*)d_in[10];
    const float* b_ih = (const float*)d_in[11];
    const float* b_hh = (const float*)d_in[12];
    const float* Wo1  = (const float*)d_in[13];
    const float* bo1  = (const float*)d_in[14];
    const float* Wo2  = (const float*)d_in[15];
    const float* bo2  = (const float*)d_in[16];

    float* ws   = (float*)d_ws;
    float*        Weff  = ws;                            // 65536
    float*        beff  = Weff + 65536;                  // 256
    float*        WhhT  = beff + 256;                    // 196608
    float*        wo    = WhhT + 196608;                 // 256
    float*        bo    = wo + 256;                      // 1
    unsigned int* Whh16 = (unsigned int*)(bo + 1);       // 79872 dwords

    prep_weff<<<256, 256, 0, stream>>>(W1, W2, b1, b2, Weff, beff);
    prep_whht<<<192, 1024, 0, stream>>>(W_hh, WhhT);
    prep_whh16<<<78, 1024, 0, stream>>>(WhhT, Whh16);
    prep_wo<<<1, 256, 0, stream>>>(Wo1, Wo2, bo1, bo2, wo, bo);

    ode_rnn_main<<<B_BATCH, 1024, 0, stream>>>(b_in, m_in, trm, tem, h0,
                                               Weff, beff, WhhT, Whh16,
                                               W_ih, b_ih, b_hh, wo, bo,
                                               (float*)d_out);
}

// Round 14
// 2091.653 us; speedup vs baseline: 3.7039x; 1.0012x over previous
//
#include <hip/hip_runtime.h>

#define H 256
#define T_STEPS 128
#define B_BATCH 256
#define I_LDS 48      // WhhT rows [0,48) persistent in LDS as f32 (147456 B)
#define N_P16 104     // packed f16 row-pairs covering gh rows [48,256)
#define XGRP 36       // words per 32-float xs segment: 8 segments hit disjoint bank-quads

#define LOG2E 1.4426950408889634f

union CVH { unsigned int u; _Float16 h[2]; };

__device__ __forceinline__ float fexp2_(float x) {
#if __has_builtin(__builtin_amdgcn_exp2f)
    return __builtin_amdgcn_exp2f(x);
#else
    return exp2f(x);
#endif
}
__device__ __forceinline__ float frcp_(float x) {
#if __has_builtin(__builtin_amdgcn_rcpf)
    float r = __builtin_amdgcn_rcpf(x);
    return r * (2.0f - x * r);          // 1 Newton step -> ~0.5 ulp
#else
    return 1.0f / x;
#endif
}
// fast tanh/sigmoid: measured bf16-exact vs np ref (rounds 8-13)
__device__ __forceinline__ float tanhf_(float x) {
    float xc = fminf(fmaxf(x, -16.f), 16.f);
    float t  = fexp2_(xc * (2.f * LOG2E));
    return (t - 1.f) * frcp_(t + 1.f);
}
__device__ __forceinline__ float sigmoidf_(float x) {
    float xc = fminf(fmaxf(x, -30.f), 30.f);
    return frcp_(1.f + fexp2_(-xc * LOG2E));
}

// ---------------- prep kernels (tiny, once per launch; cold path) ----------------

__global__ void prep_weff(const float* __restrict__ W1, const float* __restrict__ W2,
                          const float* __restrict__ b1, const float* __restrict__ b2,
                          float* __restrict__ Weff, float* __restrict__ beff) {
    int i = blockIdx.x, j = threadIdx.x;
    const float* w2row = W2 + j * H;
    float acc = 0.f;
    for (int d = 0; d < H; ++d) acc += W1[d * H + i] * w2row[d];
    Weff[i * H + j] = acc;
    if (i == 0) {
        float bacc = b2[j];
        for (int d = 0; d < H; ++d) bacc += b1[d] * w2row[d];
        beff[j] = bacc;
    }
}

// pack Weff row, col-pair {2jp,2jp+1} into one dword of 2 f16 (RNE)
__global__ void prep_weffh16(const float* __restrict__ Weff, unsigned int* __restrict__ W16) {
    int idx = blockIdx.x * 1024 + threadIdx.x;  // 32768
    int row = idx >> 7, jp = idx & 127;
    CVH cv;
    cv.h[0] = (_Float16)Weff[row * H + 2 * jp];
    cv.h[1] = (_Float16)Weff[row * H + 2 * jp + 1];
    W16[idx] = cv.u;
}

__global__ void prep_whht(const float* __restrict__ Whh, float* __restrict__ WhhT) {
    int idx = blockIdx.x * blockDim.x + threadIdx.x;  // 196608
    int i = idx / 768;
    int r = idx - i * 768;
    WhhT[idx] = Whh[r * H + i];
}

// pack gh rows {48+2i2, 49+2i2} col r of WhhT into one dword of 2 f16 (RNE)
__global__ void prep_whh16(const float* __restrict__ WhhT, unsigned int* __restrict__ W16) {
    int idx = blockIdx.x * blockDim.x + threadIdx.x;  // 79872
    if (idx >= N_P16 * 768) return;
    int i2 = idx / 768;
    int r  = idx - i2 * 768;
    CVH cv;
    cv.h[0] = (_Float16)WhhT[(I_LDS + 2 * i2) * 768 + r];
    cv.h[1] = (_Float16)WhhT[(I_LDS + 2 * i2 + 1) * 768 + r];
    W16[idx] = cv.u;
}

__global__ void prep_wo(const float* __restrict__ Wo1, const float* __restrict__ Wo2,
                        const float* __restrict__ bo1, const float* __restrict__ bo2,
                        float* __restrict__ wo, float* __restrict__ bo) {
    int i = threadIdx.x;
    float acc = 0.f;
    for (int d = 0; d < H; ++d) acc += Wo1[d * H + i] * Wo2[d];
    wo[i] = acc;
    float p = bo1[i] * Wo2[i];
    __shared__ float red[4];
    for (int off = 32; off > 0; off >>= 1) p += __shfl_down(p, off);
    if ((i & 63) == 0) red[i >> 6] = p;
    __syncthreads();
    if (i == 0) bo[0] = red[0] + red[1] + red[2] + red[3] + bo2[0];
}

// ---------------- main scan: 1 block (1024 thr) per batch row ----------------
// Round-13 structure with ONE change: Weff is packed f16 (32 dwords/thread
// instead of 64 f32).  (a) weights + working set now fit the ARCH-VGPR side
// (the 64-f32 pin lived in AGPRs; suspected v_accvgpr_read per FMA operand
// was the hidden 2x in EVAL's issue count); (b) fmaf((float)h16, f32, f32)
// maps to v_fma_mix_f32.  x, accumulation, trajectory stay f32 (round 2's
// failure quantized the published STATE; round 13 proved weight-only f16
// rounding is output-exact on the gh path).
// gh: round-10 column walk (consecutive lanes -> consecutive addresses),
// rows [0,48) f32 in LDS, rows [48,256) f16-packed stream (round 13).

__global__ __attribute__((amdgpu_flat_work_group_size(1024, 1024),
                          amdgpu_waves_per_eu(4, 4)))
void ode_rnn_main(
    const float* __restrict__ b_in, const float* __restrict__ m_in,
    const float* __restrict__ trm_in, const float* __restrict__ tem_in,
    const float* __restrict__ h0,
    const unsigned int* __restrict__ WeffH16, const float* __restrict__ beff,
    const float* __restrict__ WhhT, const unsigned int* __restrict__ Whh16,
    const float* __restrict__ W_ih, const float* __restrict__ b_ih,
    const float* __restrict__ b_hh,
    const float* __restrict__ wo, const float* __restrict__ bo_p,
    float* __restrict__ out)
{
    const int tid = threadIdx.x;
    const int bb  = blockIdx.x;
    const int jp  = tid >> 3;     // column pair 0..127
    const int e   = tid & 7;      // K-slice eighth
    const int c   = e & 1;
    const int jc  = 2 * jp + c;

    __shared__ float whh_lds[I_LDS * 768];               // 147456 B
    __shared__ __align__(16) float xsb[2][8 * XGRP];     // 2304 B
    __shared__ __align__(16) float xsf[H];               // hp (linear)
    __shared__ float gh_lds[768];
    __shared__ float red[4];
    __shared__ float times_s[T_STEPS];
    __shared__ float bv_s[T_STEPS], trm_s[T_STEPS], tem_s[T_STEPS], m_s[T_STEPS];

    // Weff tile: rows 32e..32e+31 x cols {2jp,2jp+1}, f16-packed, pinned
    unsigned int wregh[32];
    #pragma unroll
    for (int il = 0; il < 32; ++il)
        wregh[il] = WeffH16[(32 * e + il) * 128 + jp];
    #pragma unroll
    for (int il = 0; il < 32; ++il)
        asm volatile("" : "+v"(wregh[il]));

    // stage WhhT rows [0,I_LDS) + per-step scalars
    for (int k = tid; k < I_LDS * 768; k += 1024) whh_lds[k] = WhhT[k];
    if (tid < T_STEPS) {
        times_s[tid] = b_in[2 * tid];   // times identical across batch
        int bt = bb * T_STEPS + tid;
        bv_s[tid]  = b_in[2 * bt + 1];
        trm_s[tid] = trm_in[bt];
        tem_s[tid] = tem_in[bt];
        m_s[tid]   = m_in[bt];
    }

    float h = h0[bb * H + jc];
    const float be   = beff[jc];
    const float bihr = b_ih[jc], bihz = b_ih[H + jc], bihn = b_ih[2 * H + jc];
    const float bhhr = b_hh[jc], bhhz = b_hh[H + jc], bhhn = b_hh[2 * H + jc];
    const float wihr = W_ih[jc], wihz = W_ih[H + jc], wihn = W_ih[2 * H + jc];
    const float bo   = bo_p[0];
    const float wo_t = (tid >= 768) ? wo[tid - 768] : 0.f;

    // publish slot for this thread's column (valid when e < 2: then jc == 2jp+e)
    const int pubpos = (jc >> 5) * XGRP + (jc & 31);

    if (e < 2) xsb[0][pubpos] = h;     // initial publish (step 0 reads buf 0)
    __syncthreads();

    // eval: 8 broadcast b128 reads, 64 mixed-precision FMA (2 cols),
    // folded 3-shuffle reduce, fast tanh
    #define EVAL(KOUT_) do {                                       \
        const float* xp_ = &xsb[cur][e * XGRP];                    \
        float a0_ = 0.f, a1_ = 0.f, b0_ = 0.f, b1_ = 0.f;          \
        _Pragma("unroll")                                          \
        for (int g_ = 0; g_ < 8; ++g_) {                           \
            float4 x_ = ((const float4*)xp_)[g_];                  \
            CVH w0_, w1_, w2_, w3_;                                \
            w0_.u = wregh[4 * g_ + 0];                             \
            w1_.u = wregh[4 * g_ + 1];                             \
            w2_.u = wregh[4 * g_ + 2];                             \
            w3_.u = wregh[4 * g_ + 3];                             \
            a0_ = fmaf((float)w0_.h[0], x_.x, a0_);                \
            b0_ = fmaf((float)w0_.h[1], x_.x, b0_);                \
            a1_ = fmaf((float)w1_.h[0], x_.y, a1_);                \
            b1_ = fmaf((float)w1_.h[1], x_.y, b1_);                \
            a0_ = fmaf((float)w2_.h[0], x_.z, a0_);                \
            b0_ = fmaf((float)w2_.h[1], x_.z, b0_);                \
            a1_ = fmaf((float)w3_.h[0], x_.w, a1_);                \
            b1_ = fmaf((float)w3_.h[1], x_.w, b1_);                \
        }                                                          \
        float s0_ = a0_ + a1_, s1_ = b0_ + b1_;                    \
        float v_ = (c == 0) ? s0_ : s1_;                           \
        float u_ = (c == 0) ? s1_ : s0_;                           \
        v_ += __shfl_xor(u_, 1);                                   \
        v_ += __shfl_xor(v_, 2);                                   \
        v_ += __shfl_xor(v_, 4);                                   \
        KOUT_ = tanhf_(be + v_);                                   \
    } while (0)

    // publish next matvec arg (lanes e<2, one b32 each); barrier; flip
    #define PUBLISH(V_) do {                                       \
        if (e < 2) xsb[cur ^ 1][pubpos] = (V_);                    \
        __syncthreads();                                           \
        cur ^= 1;                                                  \
    } while (0)

    float tprev = 0.f;
    #pragma unroll 1
    for (int t = 0; t < T_STEPS; ++t) {
        float t1 = times_s[t];
        float dt = (t1 - tprev) * 0.5f;   // per-substep dt (N_SUB=2)
        tprev = t1;

        int cur = 0;
        float k1, k2, k3, k4;
        #pragma unroll 1
        for (int s = 0; s < 2; ++s) {
            EVAL(k1); PUBLISH(fmaf(0.5f * dt, k1, h));
            EVAL(k2); PUBLISH(fmaf(0.5f * dt, k2, h));
            EVAL(k3); PUBLISH(fmaf(dt, k3, h));
            EVAL(k4);
            h = fmaf(dt * (1.f / 6.f), k1 + 2.f * (k2 + k3) + k4, h);
            if (s == 0) PUBLISH(h);   // substep-2 k1 reads h
        }

        // stage hp (linear) for gh + out head
        if (e < 2) xsf[jc] = h;
        __syncthreads();

        // gh = hp @ W_hh^T (threads 0..767):
        //  rows [0,48): f32 from LDS, conflict-free stride-768 walk.
        //  rows [48,256): f16-packed transposed stream, consecutive lanes
        //  read consecutive dwords (256B/wave-load).
        // || out-head dot (waves 12..15)
        if (tid < 768) {
            float c0 = 0.f, c1 = 0.f, c2 = 0.f, c3 = 0.f;
            const unsigned int* wp = Whh16 + tid;
            #pragma unroll 13
            for (int ii = 0; ii < N_P16; ii += 2) {
                float4 xv = *(const float4*)(xsf + I_LDS + 2 * ii);
                CVH ca, cb;
                ca.u = wp[ii * 768];
                cb.u = wp[(ii + 1) * 768];
                c0 = fmaf(xv.x, (float)ca.h[0], c0);
                c1 = fmaf(xv.y, (float)ca.h[1], c1);
                c2 = fmaf(xv.z, (float)cb.h[0], c2);
                c3 = fmaf(xv.w, (float)cb.h[1], c3);
            }
            float g0 = 0.f, g1 = 0.f, g2 = 0.f, g3 = 0.f;
            const float* wl = whh_lds + tid;
            #pragma unroll 4
            for (int i = 0; i < I_LDS; i += 4) {
                float4 xv = *(const float4*)(xsf + i);
                g0 = fmaf(xv.x, wl[(i + 0) * 768], g0);
                g1 = fmaf(xv.y, wl[(i + 1) * 768], g1);
                g2 = fmaf(xv.z, wl[(i + 2) * 768], g2);
                g3 = fmaf(xv.w, wl[(i + 3) * 768], g3);
            }
            gh_lds[tid] = ((c0 + c1) + (c2 + c3)) + ((g0 + g1) + (g2 + g3));
        } else {
            float p = xsf[tid - 768] * wo_t;
            #pragma unroll
            for (int off = 32; off > 0; off >>= 1) p += __shfl_down(p, off);
            if ((tid & 63) == 0) red[(tid - 768) >> 6] = p;
        }
        __syncthreads();

        // gates: ALL threads compute for their jc (replicated, bit-identical)
        {
            float outv = tanhf_(red[0] + red[1] + red[2] + red[3] + bo);
            float bv = bv_s[t], trm = trm_s[t], tem = tem_s[t], mv = m_s[t];
            float ghr = gh_lds[jc] + bhhr;
            float ghz = gh_lds[256 + jc] + bhhz;
            float ghn = gh_lds[512 + jc] + bhhn;
            float x1v = bv * trm, x2v = outv * tem;

            float r1 = sigmoidf_(fmaf(x1v, wihr, bihr) + ghr);
            float z1 = sigmoidf_(fmaf(x1v, wihz, bihz) + ghz);
            float n1 = tanhf_(fmaf(x1v, wihn, bihn) + r1 * ghn);
            float h1 = (1.f - z1) * n1 + z1 * h;

            float r2 = sigmoidf_(fmaf(x2v, wihr, bihr) + ghr);
            float z2 = sigmoidf_(fmaf(x2v, wihz, bihz) + ghz);
            float n2 = tanhf_(fmaf(x2v, wihn, bihn) + r2 * ghn);
            float h2 = (1.f - z2) * n2 + z2 * h;

            if (tid == 0) out[bb * T_STEPS + t] = outv;
            h = trm * h1 + tem * h2 + (1.f - mv) * h;
        }

        // publish h_new for next step's first eval (reads buf 0)
        if (e < 2) xsb[0][pubpos] = h;
        __syncthreads();
    }
    #undef EVAL
    #undef PUBLISH
}

// ---------------- launcher ----------------

extern "C" void kernel_launch(void* const* d_in, const int* in_sizes, int n_in,
                              void* d_out, int out_size, void* d_ws, size_t ws_size,
                              hipStream_t stream) {
    const float* b_in = (const float*)d_in[0];
    const float* m_in = (const float*)d_in[1];
    const float* trm  = (const float*)d_in[2];
    const float* tem  = (const float*)d_in[3];
    const float* h0   = (const float*)d_in[4];
    const float* W1   = (const float*)d_in[5];
    const float* b1   = (const float*)d_in[6];
    const float* W2   = (const float*)d_in[7];
    const float* b2   = (const float*)d_in[8];
    const float* W_ih = (const float*)d_in[9];
    const float* W_hh = (const float*)d_in[10];
    const float* b_ih = (const float*)d_in[11];
    const float* b_hh = (const float*)d_in[12];
    const float* Wo1  = (const float*)d_in[13];
    const float* bo1  = (const float*)d_in[14];
    const float* Wo2  = (const float*)d_in[15];
    const float* bo2  = (const float*)d_in[16];

    float* ws = (float*)d_ws;
    float*        Weff    = ws;                             // 65536
    float*        beff    = Weff + 65536;                   // 256
    float*        WhhT    = beff + 256;                     // 196608
    float*        wo      = WhhT + 196608;                  // 256
    float*        bo      = wo + 256;                       // 1
    unsigned int* Whh16   = (unsigned int*)(bo + 1);        // 79872 dwords
    unsigned int* WeffH16 = Whh16 + 79872;                  // 32768 dwords

    prep_weff<<<256, 256, 0, stream>>>(W1, W2, b1, b2, Weff, beff);
    prep_weffh16<<<32, 1024, 0, stream>>>(Weff, WeffH16);
    prep_whht<<<192, 1024, 0, stream>>>(W_hh, WhhT);
    prep_whh16<<<78, 1024, 0, stream>>>(WhhT, Whh16);
    prep_wo<<<1, 256, 0, stream>>>(Wo1, Wo2, bo1, bo2, wo, bo);

    ode_rnn_main<<<B_BATCH, 1024, 0, stream>>>(b_in, m_in, trm, tem, h0,
                                               WeffH16, beff, WhhT, Whh16,
                                               W_ih, b_ih, b_hh, wo, bo,
                                               (float*)d_out);
}